// Round 1
// 170.921 us; speedup vs baseline: 1.1297x; 1.1297x over previous
//
#include <hip/hip_runtime.h>
#include <hip/hip_bf16.h>

// Capsule EM routing, fully fused: votes recomputed in registers each pass.
// B=32, H=W=8, I=32 -> N=2048, O=64, P=16, routings=3.
//
// R1: occupancy fix. Old grid was 512 blocks (2 blocks/CU -> 8 waves/CU,
// Occupancy 18.6%, VALUBusy 30%). Now each block owns ONE spatial site and
// the 4 waves split the i-loop (8 capsules each): grid = 64*32 = 2048 blocks
// = 8 blocks/CU = 32 waves/CU ceiling. A 2-slice LDS tree reduction across
// the 4 waves keeps the global atomic count identical to before (4.3M).

#define NB 32
#define NN 2048
#define NO 64
#define NP 16
#define CHUNKS 64          // blocks per batch sample = spatial sites
#define CHN (NN / CHUNKS)  // 32 n per block = 1 spatial site
#define EPSF 1e-7f

// accum layout per iteration: [b][slot][o], slots 0..15 = sum rr'*v,
// 16..31 = sum rr'*v^2, 32 = rps.  ACC_PER_B = 33*64 floats.
#define ACC_SLOTS 33
#define ACC_PER_B (ACC_SLOTS * NO)
#define ACC_TOTAL (NB * ACC_PER_B)

// stats layout per iteration: [b][slot][o], slots 0..15 = mean, 16..31 =
// 0.5/var, 32 = zz_base = log(o_act+eps) - sum_p log(sigma+eps)

template <bool FIRST>
__global__ __launch_bounds__(256) void accum_kernel(
    const float* __restrict__ pose,   // [B][N][16]
    const float* __restrict__ act,    // [B][N]
    const float* __restrict__ wmat,   // [I=32][O=64][16]
    const float* __restrict__ stats,  // [B][33][64] (prev iter) or null
    float* __restrict__ accum)        // [B][33][64] (pre-zeroed)
{
    __shared__ float pose_s[CHN * 16];            // 2 KB (one site: 32 poses)
    __shared__ float act_s[CHN];                  // 128 B
    __shared__ float red[2][ACC_SLOTS * NO];      // 16.9 KB reduce buffer

    const int b = blockIdx.y;
    const int site = blockIdx.x;     // 0..63 spatial site
    const int n0 = site * CHN;
    const int tid = threadIdx.x;

    // cooperative load of this site's poses + activations
    {
        const float4* psrc = (const float4*)(pose + ((size_t)b * NN + n0) * 16);
        float4* pdst = (float4*)pose_s;
        if (tid < CHN * 4) pdst[tid] = psrc[tid];   // 128 float4s
        if (tid < CHN) act_s[tid] = act[(size_t)b * NN + n0 + tid];
    }
    __syncthreads();

    const int wv = tid >> 6;    // wave 0..3 -> i-range [wv*8, wv*8+8)
    const int o = tid & 63;     // lane = output capsule

    float m[16], i2v[16], zzb = 0.f;
    if (!FIRST) {
        const float* st = stats + (size_t)b * ACC_PER_B;
        #pragma unroll
        for (int p = 0; p < 16; p++) m[p] = st[p * 64 + o];
        #pragma unroll
        for (int p = 0; p < 16; p++) i2v[p] = st[(16 + p) * 64 + o];
        zzb = st[32 * 64 + o];
    }

    float accR = 0.f, acc1[16], acc2[16];
    #pragma unroll
    for (int p = 0; p < 16; p++) { acc1[p] = 0.f; acc2[p] = 0.f; }

    const int hh = site >> 3, ww = site & 7;
    const float c0 = (hh + 0.5f) * 0.125f;
    const float c1 = (ww + 0.5f) * 0.125f;

    for (int ii = 0; ii < 8; ii++) {
        const int i = wv * 8 + ii;   // capsule index; n-local index == i
        const float4* wp = (const float4*)(wmat + ((size_t)i * 64 + o) * 16);
        float4 w0 = wp[0], w1 = wp[1], w2 = wp[2], w3 = wp[3];  // rows k, cols c
        const float* pr = pose_s + i * 16;  // broadcast reads (same addr all lanes)
        float v[16];
        #pragma unroll
        for (int a = 0; a < 4; a++) {
            float pa0 = pr[a * 4 + 0], pa1 = pr[a * 4 + 1];
            float pa2 = pr[a * 4 + 2], pa3 = pr[a * 4 + 3];
            v[a * 4 + 0] = pa0 * w0.x + pa1 * w1.x + pa2 * w2.x + pa3 * w3.x;
            v[a * 4 + 1] = pa0 * w0.y + pa1 * w1.y + pa2 * w2.y + pa3 * w3.y;
            v[a * 4 + 2] = pa0 * w0.z + pa1 * w1.z + pa2 * w2.z + pa3 * w3.z;
            v[a * 4 + 3] = pa0 * w0.w + pa1 * w1.w + pa2 * w2.w + pa3 * w3.w;
        }
        v[0] += c0;
        v[1] += c1;

        float rr;
        if (FIRST) {
            rr = 1.0f / 64.0f;
        } else {
            float d = zzb;
            #pragma unroll
            for (int p = 0; p < 16; p++) {
                float t = v[p] - m[p];
                d -= t * t * i2v[p];
            }
            // softmax over the 64 o-lanes (each n owned by exactly one wave)
            float mx = d;
            #pragma unroll
            for (int s = 32; s > 0; s >>= 1) mx = fmaxf(mx, __shfl_xor(mx, s, 64));
            float e = __expf(d - mx);
            float sum = e;
            #pragma unroll
            for (int s = 32; s > 0; s >>= 1) sum += __shfl_xor(sum, s, 64);
            rr = e / sum;
        }
        float rp = rr * act_s[i];
        accR += rp;
        #pragma unroll
        for (int p = 0; p < 16; p++) {
            acc1[p] += rp * v[p];
            acc2[p] += rp * v[p] * v[p];
        }
    }

    // tree-reduce the 4 waves' partials in LDS (stride-1 in o: conflict-free)
    if (wv >= 2) {
        float* r = red[wv - 2];
        r[32 * 64 + o] = accR;
        #pragma unroll
        for (int p = 0; p < 16; p++) r[p * 64 + o] = acc1[p];
        #pragma unroll
        for (int p = 0; p < 16; p++) r[(16 + p) * 64 + o] = acc2[p];
    }
    __syncthreads();
    if (wv < 2) {
        const float* r = red[wv];
        accR += r[32 * 64 + o];
        #pragma unroll
        for (int p = 0; p < 16; p++) acc1[p] += r[p * 64 + o];
        #pragma unroll
        for (int p = 0; p < 16; p++) acc2[p] += r[(16 + p) * 64 + o];
    }
    __syncthreads();
    if (wv == 1) {
        float* r = red[0];
        r[32 * 64 + o] = accR;
        #pragma unroll
        for (int p = 0; p < 16; p++) r[p * 64 + o] = acc1[p];
        #pragma unroll
        for (int p = 0; p < 16; p++) r[(16 + p) * 64 + o] = acc2[p];
    }
    __syncthreads();
    if (wv == 0) {
        const float* r = red[0];
        accR += r[32 * 64 + o];
        #pragma unroll
        for (int p = 0; p < 16; p++) acc1[p] += r[p * 64 + o];
        #pragma unroll
        for (int p = 0; p < 16; p++) acc2[p] += r[(16 + p) * 64 + o];

        float* ac = accum + (size_t)b * ACC_PER_B;
        atomicAdd(ac + 32 * 64 + o, accR);
        #pragma unroll
        for (int p = 0; p < 16; p++) atomicAdd(ac + p * 64 + o, acc1[p]);
        #pragma unroll
        for (int p = 0; p < 16; p++) atomicAdd(ac + (16 + p) * 64 + o, acc2[p]);
    }
}

__global__ __launch_bounds__(64) void stats_kernel(
    const float* __restrict__ accum,   // [B][33][64]
    const float* __restrict__ beta_v,  // [64]
    const float* __restrict__ beta_a,  // [64]
    float* __restrict__ stats_out,     // [B][33][64] or null (final)
    float* __restrict__ out,           // null unless final
    float inv_temp)
{
    const int b = blockIdx.x;
    const int o = threadIdx.x;  // 64 threads = 1 wave
    const float* ac = accum + (size_t)b * ACC_PER_B;

    float rps = ac[32 * 64 + o];
    float m[16], var[16];
    float logsum = 0.f;
    #pragma unroll
    for (int p = 0; p < 16; p++) {
        float s1 = ac[p * 64 + o];
        float s2 = ac[(16 + p) * 64 + o];
        float mm = s1 / rps;
        float vv = fmaxf(s2 / rps - mm * mm, 0.f);
        m[p] = mm;
        var[p] = vv;
        logsum += __logf(sqrtf(vv) + EPSF);
    }
    float cost = rps * (16.0f * beta_v[o] + logsum);

    // mean over O
    float cm = cost;
    #pragma unroll
    for (int s = 32; s > 0; s >>= 1) cm += __shfl_xor(cm, s, 64);
    cm *= (1.0f / 64.0f);
    // population stdv over O
    float d = cost - cm;
    float cs = d * d;
    #pragma unroll
    for (int s = 32; s > 0; s >>= 1) cs += __shfl_xor(cs, s, 64);
    cs = sqrtf(cs * (1.0f / 64.0f));

    float x = inv_temp * (beta_a[o] + (cm - cost) / (cs + EPSF));
    float oa = 1.0f / (1.0f + __expf(-x));

    if (stats_out) {
        float* st = stats_out + (size_t)b * ACC_PER_B;
        #pragma unroll
        for (int p = 0; p < 16; p++) st[p * 64 + o] = m[p];
        #pragma unroll
        for (int p = 0; p < 16; p++) st[(16 + p) * 64 + o] = 0.5f / var[p];
        st[32 * 64 + o] = __logf(oa + EPSF) - logsum;
    }
    if (out) {
        float* op = out + ((size_t)b * 64 + o) * 16;
        #pragma unroll
        for (int p = 0; p < 16; p++) op[p] = m[p];
        out[(size_t)NB * NO * NP + (size_t)b * 64 + o] = oa;
    }
}

extern "C" void kernel_launch(void* const* d_in, const int* in_sizes, int n_in,
                              void* d_out, int out_size, void* d_ws, size_t ws_size,
                              hipStream_t stream) {
    const float* pose   = (const float*)d_in[0];  // (32,8,8,32,4,4)
    const float* act    = (const float*)d_in[1];  // (32,8,8,32)
    const float* wmat   = (const float*)d_in[2];  // (32,64,4,4)
    const float* beta_v = (const float*)d_in[3];  // (1,64)
    const float* beta_a = (const float*)d_in[4];  // (1,64)
    float* out = (float*)d_out;
    float* ws = (float*)d_ws;

    float* accum0 = ws;
    float* accum1 = ws + ACC_TOTAL;
    float* accum2 = ws + 2 * (size_t)ACC_TOTAL;
    float* stats0 = ws + 3 * (size_t)ACC_TOTAL;
    float* stats1 = ws + 4 * (size_t)ACC_TOTAL;

    // zero the three accumulator regions (ws is poisoned before every call)
    hipMemsetAsync(ws, 0, 3 * (size_t)ACC_TOTAL * sizeof(float), stream);

    dim3 grid(CHUNKS, NB);
    accum_kernel<true><<<grid, 256, 0, stream>>>(pose, act, wmat, nullptr, accum0);
    stats_kernel<<<NB, 64, 0, stream>>>(accum0, beta_v, beta_a, stats0, nullptr, 1.0f);
    accum_kernel<false><<<grid, 256, 0, stream>>>(pose, act, wmat, stats0, accum1);
    stats_kernel<<<NB, 64, 0, stream>>>(accum1, beta_v, beta_a, stats1, nullptr, 2.0f);
    accum_kernel<false><<<grid, 256, 0, stream>>>(pose, act, wmat, stats1, accum2);
    stats_kernel<<<NB, 64, 0, stream>>>(accum2, beta_v, beta_a, nullptr, out, 3.0f);
}